// Round 3
// baseline (2047.183 us; speedup 1.0000x reference)
//
#include <hip/hip_runtime.h>

// Fused GNN forward with f16 MFMA (fp32 accumulate).
// 16 graphs per block, 512 threads (8 waves). All activations f16 in LDS
// (XOR-swizzled), x-residual fp32 in registers. Weights pre-transposed to
// f16 [N][K] in d_ws by prep kernel.
// R3: pin amdgpu_waves_per_eu(4,4) (128 VGPR target, kills spill traffic that
// bound R2), B-fragments loaded in nt-pairs to cut liveness.

typedef _Float16 h8 __attribute__((ext_vector_type(8)));
typedef float f4 __attribute__((ext_vector_type(4)));

constexpr int NB = 65536;
constexpr int GG = 16;                 // graphs per block
constexpr int NBLK = NB / GG;          // 4096 blocks

__device__ __forceinline__ float lrelu(float v){ return v >= 0.f ? v : 0.01f*v; }
__device__ __forceinline__ int div5(int v){ return (v*52429)>>18; }  // exact for v<131072

// LDS row stride 128 f16 (256B), XOR-swizzle bits 4-6 by row&7 (bank spread).
__device__ __forceinline__ _Float16* sw8(_Float16* b, int row, int offh){
    int byte = (row<<8) + (offh<<1);
    byte ^= (row&7)<<4;
    return (_Float16*)((char*)b + byte);
}
// ea: row stride 32 f16 (64B), XOR bits 4-5 by row&3.
__device__ __forceinline__ _Float16* swea(_Float16* b, int row, int offh){
    int byte = (row<<6) + (offh<<1);
    byte ^= (row&3)<<4;
    return (_Float16*)((char*)b + byte);
}

#define MFMA(a,b,c) __builtin_amdgcn_mfma_f32_16x16x32_f16((a),(b),(c),0,0,0)

__device__ __forceinline__ f4 z4(){ f4 v; v[0]=0.f; v[1]=0.f; v[2]=0.f; v[3]=0.f; return v; }

// ---- prep: transpose+convert weights f32[K][N] -> f16[N][K], per l ----
__global__ void prep_t(const float* __restrict__ src, _Float16* __restrict__ dst,
                       int K, int N, int total){
    int i = blockIdx.x*256 + threadIdx.x;
    if (i >= total) return;
    int kn = K*N;
    int l = i / kn; int r = i - l*kn;
    int n = r / K;  int k = r - n*K;
    dst[i] = (_Float16)src[(size_t)l*kn + (size_t)k*N + n];
}

// ws layout (f16 element offsets)
constexpr int O_MSG1 = 0;        // 4 x [128][288]
constexpr int O_MSG2 = 147456;   // 4 x [128][128]
constexpr int O_UPD1 = 212992;   // 4 x [128][256]
constexpr int O_UPD2 = 344064;   // 4 x [128][128]
constexpr int O_POOL = 409600;   // [256][640]
constexpr int O_MLP1 = 573440;   // [256][256]
constexpr int O_MLP2 = 638976;   // [64][256]

__global__ __launch_bounds__(512) __attribute__((amdgpu_waves_per_eu(4, 4)))
void gnn_mfma(const float* __restrict__ nfeat, const float* __restrict__ efeat,
              const int* __restrict__ eidx,
              const float* __restrict__ node_w, const float* __restrict__ node_b,
              const float* __restrict__ edge_w, const float* __restrict__ edge_b,
              const _Float16* __restrict__ wT,
              const float* __restrict__ msg_b1, const float* __restrict__ msg_b2,
              const float* __restrict__ upd_b1, const float* __restrict__ upd_g1, const float* __restrict__ upd_be1,
              const float* __restrict__ upd_b2, const float* __restrict__ upd_g2, const float* __restrict__ upd_be2,
              const float* __restrict__ pool_b, const float* __restrict__ pool_g, const float* __restrict__ pool_be,
              const float* __restrict__ mlp1_b, const float* __restrict__ mlp1_g, const float* __restrict__ mlp1_be,
              const float* __restrict__ mlp2_b, const float* __restrict__ mlp2_g, const float* __restrict__ mlp2_be,
              float* __restrict__ out)
{
    extern __shared__ char smem[];
    _Float16* xh  = (_Float16*)(smem);          // 80 rows x 128, swz8  (20480 B)
    _Float16* ea  = (_Float16*)(smem + 20480);  // 128 rows x 32, swea  ( 8192 B)
    _Float16* buf = (_Float16*)(smem + 28672);  // 128 rows x 128, swz8 (32768 B)
    _Float16* agg = (_Float16*)(smem + 61440);  // 80 rows x 128, swz8  (20480 B)
    float*    miscf = (float*)(smem + 61440);   // alias over agg (encoder stage)
    float*    partf = (float*)(smem + 61440);   // alias over agg (final reduce)

    const int tid  = threadIdx.x;
    const int w    = tid >> 6;
    const int lane = tid & 63;
    const int l15  = lane & 15;
    const int kg   = lane >> 4;          // k-group 0..3
    const int mgM  = w >> 1;             // message-GEMM M-group (2 mtiles of 16)
    const int ngM  = w & 1;              // N-group (64 cols)
    const int mgU  = w >> 1;             // update-GEMM M-group over 5 mtiles
    const int cntU = (mgU < 2) ? 2 : ((mgU == 2) ? 1 : 0);
    const int gbase = blockIdx.x * GG;

    // ---- edge index decode (int32 or int64), packed 4-bit ----
    int dp = 0, sp = 0;
    {
        bool is64 = true;
        #pragma unroll
        for (int i = 1; i < 16; i += 2) if (eidx[i] != 0) is64 = false;
        #pragma unroll
        for (int e = 0; e < 8; ++e){
            int s = is64 ? eidx[2*e]     : eidx[e];
            int d = is64 ? eidx[16+2*e]  : eidx[8+e];
            sp |= s << (4*e); dp |= d << (4*e);
        }
    }
    const int eMine = l15 & 7;
    const int myDst = (dp >> (4*eMine)) & 15;
    const int mySrc = (sp >> (4*eMine)) & 15;

    // ---- encoder: stage nf/ef ----
    for (int i = tid; i < 816; i += 512){
        if (i < 560) miscf[i] = nfeat[(size_t)gbase*35 + i];
        else         miscf[i] = efeat[(size_t)gbase*16 + (i - 560)];
    }
    __syncthreads();

    // ea = ef @ edge_w + edge_b  (f16, 512 h8-units, 1 per thread)
    {
        int u  = tid;
        int ge = u >> 2, c8 = (u & 3) * 8;
        int g  = ge >> 3, e = ge & 7;
        float f0 = miscf[560 + g*16 + e*2];
        float f1 = miscf[560 + g*16 + e*2 + 1];
        h8 v;
        #pragma unroll
        for (int j = 0; j < 8; ++j){
            int c = c8 + j;
            v[j] = (_Float16)(edge_b[c] + f0*edge_w[c] + f1*edge_w[32 + c]);
        }
        *(h8*)swea(ea, ge, c8) = v;
    }

    // x = nf @ node_w + node_b : fp32 regs (ownership = update C-layout) + xh f16
    float xreg[2][4][4];
    #pragma unroll
    for (int mi = 0; mi < 2; ++mi){
        if (mi < cntU){
            int mt = mgU*2 + mi;
            #pragma unroll
            for (int nt = 0; nt < 4; ++nt){
                int col = ngM*64 + nt*16 + l15;
                float w0 = node_w[0*128+col], w1 = node_w[1*128+col],
                      w2 = node_w[2*128+col], w3 = node_w[3*128+col],
                      w4 = node_w[4*128+col], w5 = node_w[5*128+col],
                      w6 = node_w[6*128+col];
                float bb = node_b[col];
                #pragma unroll
                for (int r = 0; r < 4; ++r){
                    int row = mt*16 + kg*4 + r;
                    int g = div5(row), n = row - 5*g;
                    const float* nf = &miscf[g*35 + n*7];
                    float v = bb + nf[0]*w0 + nf[1]*w1 + nf[2]*w2 + nf[3]*w3
                                 + nf[4]*w4 + nf[5]*w5 + nf[6]*w6;
                    xreg[mi][nt][r] = v;
                    *sw8(xh, row, col) = (_Float16)v;
                }
            }
        }
    }
    __syncthreads();

    // ---- 4 message-passing layers ----
    for (int l = 0; l < 4; ++l){
        const _Float16* W1 = wT + O_MSG1 + (size_t)l*36864;
        const _Float16* W2 = wT + O_MSG2 + (size_t)l*16384;
        const _Float16* W3 = wT + O_UPD1 + (size_t)l*32768;
        const _Float16* W4 = wT + O_UPD2 + (size_t)l*16384;

        // ===== GEMM1: m1 = lrelu([x_dst | x_src | ea] @ W1 + b1)  M=128 K=288 N=128
        {
            f4 acc[2][4];
            #pragma unroll
            for (int mi=0;mi<2;++mi){ acc[mi][0]=z4(); acc[mi][1]=z4(); acc[mi][2]=z4(); acc[mi][3]=z4(); }
            int xrow_d[2], xrow_s[2], earow[2];
            #pragma unroll
            for (int mi = 0; mi < 2; ++mi){
                int mt = mgM*2 + mi;
                int g  = mt*2 + (l15 >> 3);
                xrow_d[mi] = g*5 + myDst;
                xrow_s[mi] = g*5 + mySrc;
                earow[mi]  = mt*16 + l15;
            }
            const _Float16* Bp = W1 + (size_t)(ngM*64 + l15)*288 + kg*8;
            #pragma unroll
            for (int kc = 0; kc < 4; ++kc){          // k 0..127 : x[dst]
                h8 a0 = *(const h8*)sw8(xh, xrow_d[0], kc*32 + kg*8);
                h8 a1 = *(const h8*)sw8(xh, xrow_d[1], kc*32 + kg*8);
                #pragma unroll
                for (int np = 0; np < 2; ++np){
                    h8 b0 = *(const h8*)(Bp + (2*np+0)*4608 + kc*32);
                    h8 b1 = *(const h8*)(Bp + (2*np+1)*4608 + kc*32);
                    acc[0][2*np]=MFMA(a0,b0,acc[0][2*np]); acc[0][2*np+1]=MFMA(a0,b1,acc[0][2*np+1]);
                    acc[1][2*np]=MFMA(a1,b0,acc[1][2*np]); acc[1][2*np+1]=MFMA(a1,b1,acc[1][2*np+1]);
                }
            }
            #pragma unroll
            for (int kc = 0; kc < 4; ++kc){          // k 128..255 : x[src]
                h8 a0 = *(const h8*)sw8(xh, xrow_s[0], kc*32 + kg*8);
                h8 a1 = *(const h8*)sw8(xh, xrow_s[1], kc*32 + kg*8);
                #pragma unroll
                for (int np = 0; np < 2; ++np){
                    h8 b0 = *(const h8*)(Bp + (2*np+0)*4608 + 128 + kc*32);
                    h8 b1 = *(const h8*)(Bp + (2*np+1)*4608 + 128 + kc*32);
                    acc[0][2*np]=MFMA(a0,b0,acc[0][2*np]); acc[0][2*np+1]=MFMA(a0,b1,acc[0][2*np+1]);
                    acc[1][2*np]=MFMA(a1,b0,acc[1][2*np]); acc[1][2*np+1]=MFMA(a1,b1,acc[1][2*np+1]);
                }
            }
            {                                         // k 256..287 : ea
                h8 a0 = *(const h8*)swea(ea, earow[0], kg*8);
                h8 a1 = *(const h8*)swea(ea, earow[1], kg*8);
                #pragma unroll
                for (int np = 0; np < 2; ++np){
                    h8 b0 = *(const h8*)(Bp + (2*np+0)*4608 + 256);
                    h8 b1 = *(const h8*)(Bp + (2*np+1)*4608 + 256);
                    acc[0][2*np]=MFMA(a0,b0,acc[0][2*np]); acc[0][2*np+1]=MFMA(a0,b1,acc[0][2*np+1]);
                    acc[1][2*np]=MFMA(a1,b0,acc[1][2*np]); acc[1][2*np+1]=MFMA(a1,b1,acc[1][2*np+1]);
                }
            }
            #pragma unroll
            for (int mi = 0; mi < 2; ++mi){
                int mt = mgM*2 + mi;
                #pragma unroll
                for (int nt = 0; nt < 4; ++nt){
                    int col = ngM*64 + nt*16 + l15;
                    float bb = msg_b1[l*128 + col];
                    #pragma unroll
                    for (int r = 0; r < 4; ++r){
                        int row = mt*16 + kg*4 + r;
                        *sw8(buf, row, col) = (_Float16)lrelu(acc[mi][nt][r] + bb);
                    }
                }
            }
        }
        __syncthreads();

        // ===== GEMM2: m2 = lrelu(m1 @ W2 + b2)  M=128 K=128 N=128 (acc in regs)
        {
            f4 acc[2][4];
            #pragma unroll
            for (int mi=0;mi<2;++mi){ acc[mi][0]=z4(); acc[mi][1]=z4(); acc[mi][2]=z4(); acc[mi][3]=z4(); }
            const _Float16* Bp = W2 + (size_t)(ngM*64 + l15)*128 + kg*8;
            #pragma unroll
            for (int kc = 0; kc < 4; ++kc){
                h8 a0 = *(const h8*)sw8(buf, (mgM*2+0)*16 + l15, kc*32 + kg*8);
                h8 a1 = *(const h8*)sw8(buf, (mgM*2+1)*16 + l15, kc*32 + kg*8);
                #pragma unroll
                for (int np = 0; np < 2; ++np){
                    h8 b0 = *(const h8*)(Bp + (2*np+0)*2048 + kc*32);
                    h8 b1 = *(const h8*)(Bp + (2*np+1)*2048 + kc*32);
                    acc[0][2*np]=MFMA(a0,b0,acc[0][2*np]); acc[0][2*np+1]=MFMA(a0,b1,acc[0][2*np+1]);
                    acc[1][2*np]=MFMA(a1,b0,acc[1][2*np]); acc[1][2*np+1]=MFMA(a1,b1,acc[1][2*np+1]);
                }
            }
            __syncthreads();   // all m1 reads done before overwrite
            #pragma unroll
            for (int mi = 0; mi < 2; ++mi){
                int mt = mgM*2 + mi;
                #pragma unroll
                for (int nt = 0; nt < 4; ++nt){
                    int col = ngM*64 + nt*16 + l15;
                    float bb = msg_b2[l*128 + col];
                    #pragma unroll
                    for (int r = 0; r < 4; ++r){
                        int row = mt*16 + kg*4 + r;
                        *sw8(buf, row, col) = (_Float16)lrelu(acc[mi][nt][r] + bb);
                    }
                }
            }
        }
        __syncthreads();

        // ===== agg[n] = sum_{e: dst[e]==n} m2[e]   (1280 h8-units)
        for (int u = tid; u < 1280; u += 512){
            int gn = u >> 4, c8 = (u & 15)*8;
            int g = div5(gn), n = gn - 5*g;
            float s0=0,s1=0,s2=0,s3=0,s4=0,s5=0,s6=0,s7=0;
            #pragma unroll
            for (int e = 0; e < 8; ++e){
                if (((dp >> (4*e)) & 15) == n){
                    h8 v = *(const h8*)sw8(buf, g*8 + e, c8);
                    s0+=(float)v[0]; s1+=(float)v[1]; s2+=(float)v[2]; s3+=(float)v[3];
                    s4+=(float)v[4]; s5+=(float)v[5]; s6+=(float)v[6]; s7+=(float)v[7];
                }
            }
            h8 o;
            o[0]=(_Float16)s0; o[1]=(_Float16)s1; o[2]=(_Float16)s2; o[3]=(_Float16)s3;
            o[4]=(_Float16)s4; o[5]=(_Float16)s5; o[6]=(_Float16)s6; o[7]=(_Float16)s7;
            *(h8*)sw8(agg, gn, c8) = o;
        }
        __syncthreads();

        // ===== GEMM3: u1 = lrelu(([x|agg]@W3 + b)*g1[n] + be1[n])  M=80 K=256 N=128
        if (cntU > 0){
            f4 acc[2][4];
            #pragma unroll
            for (int mi=0;mi<2;++mi){ acc[mi][0]=z4(); acc[mi][1]=z4(); acc[mi][2]=z4(); acc[mi][3]=z4(); }
            const _Float16* Bp = W3 + (size_t)(ngM*64 + l15)*256 + kg*8;
            #pragma unroll
            for (int kc = 0; kc < 8; ++kc){
                h8 a0, a1;
                if (kc < 4) { a0 = *(const h8*)sw8(xh,  (mgU*2+0)*16 + l15, kc*32 + kg*8); }
                else        { a0 = *(const h8*)sw8(agg, (mgU*2+0)*16 + l15, (kc-4)*32 + kg*8); }
                if (cntU > 1){
                    if (kc < 4) { a1 = *(const h8*)sw8(xh,  (mgU*2+1)*16 + l15, kc*32 + kg*8); }
                    else        { a1 = *(const h8*)sw8(agg, (mgU*2+1)*16 + l15, (kc-4)*32 + kg*8); }
                } else a1 = a0;
                #pragma unroll
                for (int np = 0; np < 2; ++np){
                    h8 b0 = *(const h8*)(Bp + (2*np+0)*4096 + kc*32);
                    h8 b1 = *(const h8*)(Bp + (2*np+1)*4096 + kc*32);
                    acc[0][2*np]=MFMA(a0,b0,acc[0][2*np]); acc[0][2*np+1]=MFMA(a0,b1,acc[0][2*np+1]);
                    if (cntU > 1){
                        acc[1][2*np]=MFMA(a1,b0,acc[1][2*np]); acc[1][2*np+1]=MFMA(a1,b1,acc[1][2*np+1]);
                    }
                }
            }
            #pragma unroll
            for (int mi = 0; mi < 2; ++mi){
                if (mi < cntU){
                    int mt = mgU*2 + mi;
                    #pragma unroll
                    for (int nt = 0; nt < 4; ++nt){
                        int col = ngM*64 + nt*16 + l15;
                        float bb = upd_b1[l*128 + col];
                        #pragma unroll
                        for (int r = 0; r < 4; ++r){
                            int crow = mt*16 + kg*4 + r;
                            int n = crow - 5*div5(crow);
                            float val = lrelu((acc[mi][nt][r] + bb)*upd_g1[l*5+n] + upd_be1[l*5+n]);
                            *sw8(buf, crow, col) = (_Float16)val;
                        }
                    }
                }
            }
        }
        __syncthreads();

        // ===== GEMM4: x += lrelu((u1@W4 + b)*g2[n] + be2[n])  M=80 K=128 N=128
        if (cntU > 0){
            f4 acc[2][4];
            #pragma unroll
            for (int mi=0;mi<2;++mi){ acc[mi][0]=z4(); acc[mi][1]=z4(); acc[mi][2]=z4(); acc[mi][3]=z4(); }
            const _Float16* Bp = W4 + (size_t)(ngM*64 + l15)*128 + kg*8;
            #pragma unroll
            for (int kc = 0; kc < 4; ++kc){
                h8 a0 = *(const h8*)sw8(buf, (mgU*2+0)*16 + l15, kc*32 + kg*8);
                h8 a1 = (cntU > 1) ? *(const h8*)sw8(buf, (mgU*2+1)*16 + l15, kc*32 + kg*8) : a0;
                #pragma unroll
                for (int np = 0; np < 2; ++np){
                    h8 b0 = *(const h8*)(Bp + (2*np+0)*2048 + kc*32);
                    h8 b1 = *(const h8*)(Bp + (2*np+1)*2048 + kc*32);
                    acc[0][2*np]=MFMA(a0,b0,acc[0][2*np]); acc[0][2*np+1]=MFMA(a0,b1,acc[0][2*np+1]);
                    if (cntU > 1){
                        acc[1][2*np]=MFMA(a1,b0,acc[1][2*np]); acc[1][2*np+1]=MFMA(a1,b1,acc[1][2*np+1]);
                    }
                }
            }
            #pragma unroll
            for (int mi = 0; mi < 2; ++mi){
                if (mi < cntU){
                    int mt = mgU*2 + mi;
                    #pragma unroll
                    for (int nt = 0; nt < 4; ++nt){
                        int col = ngM*64 + nt*16 + l15;
                        float bb = upd_b2[l*128 + col];
                        #pragma unroll
                        for (int r = 0; r < 4; ++r){
                            int crow = mt*16 + kg*4 + r;
                            int n = crow - 5*div5(crow);
                            float val = lrelu((acc[mi][nt][r] + bb)*upd_g2[l*5+n] + upd_be2[l*5+n]);
                            xreg[mi][nt][r] += val;
                            *sw8(xh, crow, col) = (_Float16)xreg[mi][nt][r];
                        }
                    }
                }
            }
        }
        __syncthreads();
    }

    // ===== pool: p = lrelu((x.flat @ poolW + b)*g + be)  M=16 K=640 N=256
    {
        f4 accP[2]; accP[0]=z4(); accP[1]=z4();
        const _Float16* Bp = wT + O_POOL + (size_t)(w*32 + l15)*640 + kg*8;
        #pragma unroll
        for (int kc = 0; kc < 20; ++kc){
            int k0 = kc*32 + kg*8;
            int n  = k0 >> 7, d = k0 & 127;
            h8 a  = *(const h8*)sw8(xh, l15*5 + n, d);
            h8 b0 = *(const h8*)(Bp + kc*32);
            h8 b1 = *(const h8*)(Bp + 16*640 + kc*32);
            accP[0]=MFMA(a,b0,accP[0]); accP[1]=MFMA(a,b1,accP[1]);
        }
        #pragma unroll
        for (int nt = 0; nt < 2; ++nt){
            int col = w*32 + nt*16 + l15;
            float pb = pool_b[col], pg = pool_g[col], pe = pool_be[col];
            #pragma unroll
            for (int r = 0; r < 4; ++r){
                int g = kg*4 + r;
                float val = lrelu((accP[nt][r] + pb)*pg + pe);
                int prow = g + 16*(col >> 7);
                *sw8(buf, prow, col & 127) = (_Float16)val;
            }
        }
    }
    __syncthreads();

    // ===== mlp1: q = lrelu((p@W + b)*g + be)  M=16 K=256 N=256
    {
        f4 accQ[2]; accQ[0]=z4(); accQ[1]=z4();
        const _Float16* Bp = wT + O_MLP1 + (size_t)(w*32 + l15)*256 + kg*8;
        #pragma unroll
        for (int kc = 0; kc < 8; ++kc){
            int k0 = kc*32 + kg*8;
            int arow = l15 + 16*(k0 >> 7);
            h8 a  = *(const h8*)sw8(buf, arow, k0 & 127);
            h8 b0 = *(const h8*)(Bp + kc*32);
            h8 b1 = *(const h8*)(Bp + 16*256 + kc*32);
            accQ[0]=MFMA(a,b0,accQ[0]); accQ[1]=MFMA(a,b1,accQ[1]);
        }
        __syncthreads();
        #pragma unroll
        for (int nt = 0; nt < 2; ++nt){
            int col = w*32 + nt*16 + l15;
            float qb = mlp1_b[col], qg = mlp1_g[col], qe = mlp1_be[col];
            #pragma unroll
            for (int r = 0; r < 4; ++r){
                int g = kg*4 + r;
                float val = lrelu((accQ[nt][r] + qb)*qg + qe);
                int qrow = 32 + g + 16*(col >> 7);
                *sw8(buf, qrow, col & 127) = (_Float16)val;
            }
        }
    }
    __syncthreads();

    // ===== mlp2 + mean: M=16 K=256 N=64 (waves 0-3), then reduce over 64 cols
    if (w < 4){
        f4 accR = z4();
        const _Float16* Bp = wT + O_MLP2 + (size_t)(w*16 + l15)*256 + kg*8;
        #pragma unroll
        for (int kc = 0; kc < 8; ++kc){
            int k0 = kc*32 + kg*8;
            int arow = 32 + l15 + 16*(k0 >> 7);
            h8 a = *(const h8*)sw8(buf, arow, k0 & 127);
            h8 b = *(const h8*)(Bp + kc*32);
            accR = MFMA(a, b, accR);
        }
        int col = w*16 + l15;
        float rb = mlp2_b[col], rg = mlp2_g[col], re = mlp2_be[col];
        #pragma unroll
        for (int r = 0; r < 4; ++r){
            float val = lrelu((accR[r] + rb)*rg + re);
            val += __shfl_xor(val, 1);
            val += __shfl_xor(val, 2);
            val += __shfl_xor(val, 4);
            val += __shfl_xor(val, 8);
            if (l15 == 0) partf[w*16 + (kg*4 + r)] = val;
        }
    }
    __syncthreads();
    if (tid < 16){
        float s = partf[tid] + partf[16+tid] + partf[32+tid] + partf[48+tid];
        out[gbase + tid] = s * (1.0f/64.0f);
    }
}

extern "C" void kernel_launch(void* const* d_in, const int* in_sizes, int n_in,
                              void* d_out, int out_size, void* d_ws, size_t ws_size,
                              hipStream_t stream) {
    _Float16* wT = (_Float16*)d_ws;
    auto T = [&](const void* src, int dstoff, int L, int K, int N){
        int total = L*K*N;
        prep_t<<<(total + 255)/256, 256, 0, stream>>>((const float*)src, wT + dstoff, K, N, total);
    };
    T(d_in[7],  O_MSG1, 4, 288, 128);
    T(d_in[9],  O_MSG2, 4, 128, 128);
    T(d_in[11], O_UPD1, 4, 256, 128);
    T(d_in[15], O_UPD2, 4, 128, 128);
    T(d_in[19], O_POOL, 1, 640, 256);
    T(d_in[23], O_MLP1, 1, 256, 256);
    T(d_in[27], O_MLP2, 1, 256, 64);

    gnn_mfma<<<NBLK, 512, 81920, stream>>>(
        (const float*)d_in[0], (const float*)d_in[1], (const int*)d_in[2],
        (const float*)d_in[3], (const float*)d_in[4],
        (const float*)d_in[5], (const float*)d_in[6],
        wT,
        (const float*)d_in[8],  (const float*)d_in[10],
        (const float*)d_in[12], (const float*)d_in[13], (const float*)d_in[14],
        (const float*)d_in[16], (const float*)d_in[17], (const float*)d_in[18],
        (const float*)d_in[20], (const float*)d_in[21], (const float*)d_in[22],
        (const float*)d_in[24], (const float*)d_in[25], (const float*)d_in[26],
        (const float*)d_in[28], (const float*)d_in[29], (const float*)d_in[30],
        (float*)d_out);
}